// Round 1
// baseline (337.577 us; speedup 1.0000x reference)
//
#include <hip/hip_runtime.h>
#include <cstdint>

// Top-k (k=384) along last axis (C=768) of [B=16, N=4096, C=768] fp32, scatter
// values back, zeros elsewhere. One wave (64 lanes) per row; exact radix-select
// on monotone uint32 keys, 8-bit digits, early exit. Tie-break = lowest index
// (matches jax.lax.top_k).

constexpr int C    = 768;
constexpr int TPB  = 64;
constexpr int EPL  = C / TPB;   // 12 elements per lane
constexpr int NV   = EPL / 4;   // 3 float4 loads per lane

__device__ __forceinline__ uint32_t f2key(float f, uint32_t flip) {
    uint32_t b = __float_as_uint(f);
    uint32_t u = (b & 0x80000000u) ? ~b : (b | 0x80000000u); // larger float -> larger u
    return u ^ flip;                                          // flip==~0 for largest=0
}

__global__ __launch_bounds__(TPB) void topk_scatter_row(
        const float* __restrict__ x,
        const int*   __restrict__ pk,
        const int*   __restrict__ plg,
        float*       __restrict__ out) {
    __shared__ int hist[256];

    const int  lane = threadIdx.x;
    const size_t row = blockIdx.x;
    const float* xr  = x   + row * C;
    float*       orow = out + row * C;

    const int      k    = pk[0];
    const uint32_t flip = (plg[0] != 0) ? 0u : 0xFFFFFFFFu;

    float    v[EPL];
    uint32_t key[EPL];
    // element e = j*4+c lives at row index j*256 + lane*4 + c (coalesced float4)
    #pragma unroll
    for (int j = 0; j < NV; ++j) {
        float4 t = ((const float4*)xr)[j * 64 + lane];
        v[j*4+0] = t.x; v[j*4+1] = t.y; v[j*4+2] = t.z; v[j*4+3] = t.w;
    }
    #pragma unroll
    for (int e = 0; e < EPL; ++e) key[e] = f2key(v[e], flip);

    if (k <= 0) {
        #pragma unroll
        for (int j = 0; j < NV; ++j)
            ((float4*)orow)[j * 64 + lane] = make_float4(0.f, 0.f, 0.f, 0.f);
        return;
    }

    uint32_t prefix = 0;
    int      kk     = k;
    int      shift  = 24;
    bool     need_tie = false;

    for (int r = 0; r < 4; ++r) {
        // clear histogram: 64 lanes x int4 = 256 bins
        ((int4*)hist)[lane] = make_int4(0, 0, 0, 0);
        __syncthreads();

        const uint32_t pmask = (r == 0) ? 0u : ~((1u << (shift + 8)) - 1u);
        #pragma unroll
        for (int e = 0; e < EPL; ++e) {
            if (((key[e] ^ prefix) & pmask) == 0)
                atomicAdd(&hist[(key[e] >> shift) & 255u], 1);
        }
        __syncthreads();

        // lane owns digits [lane*4 .. lane*4+3]
        int4 b = ((const int4*)hist)[lane];
        int t0 = b.x + b.y + b.z + b.w;

        // inclusive suffix sum of t0 across lanes (high digits = high lanes)
        int s = t0;
        #pragma unroll
        for (int off = 1; off < 64; off <<= 1) {
            int o = __shfl_down(s, off);
            s += (lane + off < 64) ? o : 0;
        }
        const int upper = s - t0; // sum over lanes > lane

        int ge[4];
        ge[3] = upper + b.w;
        ge[2] = ge[3] + b.z;
        ge[1] = ge[2] + b.y;
        ge[0] = ge[1] + b.x;
        const int bins[4] = { b.x, b.y, b.z, b.w };

        int found_d = -1, found_gt = 0, found_bc = 0;
        #pragma unroll
        for (int i = 0; i < 4; ++i) {
            int gt = ge[i] - bins[i];
            if (gt < kk && kk <= ge[i]) {
                found_d = lane * 4 + i; found_gt = gt; found_bc = bins[i];
            }
        }
        unsigned long long m = __ballot(found_d >= 0);
        int src = __ffsll((long long)m) - 1;
        int d  = __shfl(found_d, src);
        int gt = __shfl(found_gt, src);
        int bc = __shfl(found_bc, src);

        kk -= gt;
        prefix |= ((uint32_t)d) << shift;

        if (kk == bc) break;                 // whole bin selected: sel = key >= prefix
        if (shift == 0) { need_tie = true; break; }
        shift -= 8;
        __syncthreads();                      // before next round's hist clear
    }

    // Rare: duplicates of the exact threshold key straddle the boundary.
    uint32_t selmask = 0;
    if (need_tie) {
        int base = 0;
        #pragma unroll
        for (int j = 0; j < NV; ++j) {
            int eq[4], le = 0;
            #pragma unroll
            for (int c = 0; c < 4; ++c) { eq[c] = (key[j*4+c] == prefix) ? 1 : 0; le += eq[c]; }
            // exclusive prefix over lanes (index order within a j-slice is lane-major)
            int p = le;
            #pragma unroll
            for (int off = 1; off < 64; off <<= 1) {
                int o = __shfl_up(p, off);
                p += (lane >= off) ? o : 0;
            }
            const int excl = p - le;
            const int tot  = __shfl(p, 63);
            int acc = base + excl;
            #pragma unroll
            for (int c = 0; c < 4; ++c) {
                if (eq[c] && acc < kk) selmask |= 1u << (j*4+c);
                acc += eq[c];
            }
            base += tot;
        }
    }

    #pragma unroll
    for (int j = 0; j < NV; ++j) {
        float4 o;
        float* oo = (float*)&o;
        #pragma unroll
        for (int c = 0; c < 4; ++c) {
            const int e = j*4 + c;
            bool sel = need_tie ? ((key[e] > prefix) || ((selmask >> e) & 1u))
                                : (key[e] >= prefix);
            oo[c] = sel ? v[e] : 0.0f;
        }
        ((float4*)orow)[j * 64 + lane] = o;
    }
}

extern "C" void kernel_launch(void* const* d_in, const int* in_sizes, int n_in,
                              void* d_out, int out_size, void* d_ws, size_t ws_size,
                              hipStream_t stream) {
    const float* x   = (const float*)d_in[0];
    const int*   pk  = (const int*)d_in[1];
    const int*   plg = (const int*)d_in[2];
    float*       out = (float*)d_out;

    const int rows = in_sizes[0] / C;   // 16*4096 = 65536
    topk_scatter_row<<<rows, TPB, 0, stream>>>(x, pk, plg, out);
}

// Round 2
// 337.538 us; speedup vs baseline: 1.0001x; 1.0001x over previous
//
#include <hip/hip_runtime.h>
#include <cstdint>

// Top-k (k=384) along last axis (C=768) of [B=16, N=4096, C=768] fp32, scatter
// values back, zeros elsewhere. One wave (64 lanes) per row, 4 rows per
// 256-thread block, wave-private LDS histograms => ZERO __syncthreads.
// Exact radix-select on monotone uint32 keys, 8-bit digits, early exit.
// Tie-break = lowest index (matches jax.lax.top_k).

constexpr int C    = 768;
constexpr int TPB  = 256;
constexpr int WPB  = TPB / 64;  // 4 waves (rows) per block
constexpr int EPL  = C / 64;    // 12 elements per lane
constexpr int NV   = EPL / 4;   // 3 float4 loads per lane

__device__ __forceinline__ uint32_t f2key(float f, uint32_t flip) {
    uint32_t b = __float_as_uint(f);
    uint32_t u = (b & 0x80000000u) ? ~b : (b | 0x80000000u); // larger float -> larger u
    return u ^ flip;                                          // flip==~0 for largest=0
}

__global__ __launch_bounds__(TPB) void topk_scatter_row(
        const float* __restrict__ x,
        const int*   __restrict__ pk,
        const int*   __restrict__ plg,
        float*       __restrict__ out,
        int rows) {
    __shared__ int hist_all[WPB][256];

    const int lane = threadIdx.x & 63;
    const int wid  = threadIdx.x >> 6;
    const int row  = blockIdx.x * WPB + wid;
    if (row >= rows) return;

    int* hist = hist_all[wid];   // wave-private: no barriers needed, ever

    const float* xr   = x   + (size_t)row * C;
    float*       orow = out + (size_t)row * C;

    const int      k    = pk[0];
    const uint32_t flip = (plg[0] != 0) ? 0u : 0xFFFFFFFFu;

    float    v[EPL];
    uint32_t key[EPL];
    // element e = j*4+c lives at row index j*256 + lane*4 + c (coalesced float4)
    #pragma unroll
    for (int j = 0; j < NV; ++j) {
        float4 t = ((const float4*)xr)[j * 64 + lane];
        v[j*4+0] = t.x; v[j*4+1] = t.y; v[j*4+2] = t.z; v[j*4+3] = t.w;
    }
    #pragma unroll
    for (int e = 0; e < EPL; ++e) key[e] = f2key(v[e], flip);

    if (k <= 0) {
        #pragma unroll
        for (int j = 0; j < NV; ++j)
            ((float4*)orow)[j * 64 + lane] = make_float4(0.f, 0.f, 0.f, 0.f);
        return;
    }

    uint32_t prefix = 0;
    int      kk     = k;
    int      shift  = 24;
    bool     need_tie = false;

    for (int r = 0; r < 4; ++r) {
        // clear wave-private histogram: 64 lanes x int4 = 256 bins
        ((int4*)hist)[lane] = make_int4(0, 0, 0, 0);
        // single wave, in-order DS pipe: adds below see the cleared bins

        const uint32_t pmask = (r == 0) ? 0u : ~((1u << (shift + 8)) - 1u);
        #pragma unroll
        for (int e = 0; e < EPL; ++e) {
            if (((key[e] ^ prefix) & pmask) == 0)
                atomicAdd(&hist[(key[e] >> shift) & 255u], 1);
        }

        // lane owns digits [lane*4 .. lane*4+3] (in-order DS => adds visible)
        int4 b = ((const int4*)hist)[lane];
        int t0 = b.x + b.y + b.z + b.w;

        // inclusive suffix sum of t0 across lanes (high digits = high lanes)
        int s = t0;
        #pragma unroll
        for (int off = 1; off < 64; off <<= 1) {
            int o = __shfl_down(s, off);
            s += (lane + off < 64) ? o : 0;
        }
        const int upper = s - t0; // sum over lanes > lane

        int ge[4];
        ge[3] = upper + b.w;
        ge[2] = ge[3] + b.z;
        ge[1] = ge[2] + b.y;
        ge[0] = ge[1] + b.x;
        const int bins[4] = { b.x, b.y, b.z, b.w };

        int found_d = -1, found_gt = 0, found_bc = 0;
        #pragma unroll
        for (int i = 0; i < 4; ++i) {
            int gt = ge[i] - bins[i];
            if (gt < kk && kk <= ge[i]) {
                found_d = lane * 4 + i; found_gt = gt; found_bc = bins[i];
            }
        }
        unsigned long long m = __ballot(found_d >= 0);
        int src = __ffsll((long long)m) - 1;
        int d  = __shfl(found_d, src);
        int gt = __shfl(found_gt, src);
        int bc = __shfl(found_bc, src);

        kk -= gt;
        prefix |= ((uint32_t)d) << shift;

        if (kk == bc) break;                 // whole bin selected: sel = key >= prefix
        if (shift == 0) { need_tie = true; break; }
        shift -= 8;
    }

    // Rare: duplicates of the exact threshold key straddle the boundary.
    uint32_t selmask = 0;
    if (need_tie) {
        int base = 0;
        #pragma unroll
        for (int j = 0; j < NV; ++j) {
            int eq[4], le = 0;
            #pragma unroll
            for (int c = 0; c < 4; ++c) { eq[c] = (key[j*4+c] == prefix) ? 1 : 0; le += eq[c]; }
            // exclusive prefix over lanes (index order within a j-slice is lane-major)
            int p = le;
            #pragma unroll
            for (int off = 1; off < 64; off <<= 1) {
                int o = __shfl_up(p, off);
                p += (lane >= off) ? o : 0;
            }
            const int excl = p - le;
            const int tot  = __shfl(p, 63);
            int acc = base + excl;
            #pragma unroll
            for (int c = 0; c < 4; ++c) {
                if (eq[c] && acc < kk) selmask |= 1u << (j*4+c);
                acc += eq[c];
            }
            base += tot;
        }
    }

    #pragma unroll
    for (int j = 0; j < NV; ++j) {
        float4 o;
        float* oo = (float*)&o;
        #pragma unroll
        for (int c = 0; c < 4; ++c) {
            const int e = j*4 + c;
            bool sel = need_tie ? ((key[e] > prefix) || ((selmask >> e) & 1u))
                                : (key[e] >= prefix);
            oo[c] = sel ? v[e] : 0.0f;
        }
        ((float4*)orow)[j * 64 + lane] = o;
    }
}

extern "C" void kernel_launch(void* const* d_in, const int* in_sizes, int n_in,
                              void* d_out, int out_size, void* d_ws, size_t ws_size,
                              hipStream_t stream) {
    const float* x   = (const float*)d_in[0];
    const int*   pk  = (const int*)d_in[1];
    const int*   plg = (const int*)d_in[2];
    float*       out = (float*)d_out;

    const int rows   = in_sizes[0] / C;           // 16*4096 = 65536
    const int blocks = (rows + WPB - 1) / WPB;    // 16384
    topk_scatter_row<<<blocks, TPB, 0, stream>>>(x, pk, plg, out, rows);
}